// Round 6
// baseline (98.092 us; speedup 1.0000x reference)
//
#include <hip/hip_runtime.h>
#include <math.h>

// Spherical voxelization: points [B,N,3] f32 -> hist [B,1,5,30,15] f32
// B=16, N=65536, bins = 5*30*15 = 2250.
// R6 theory: float atomicAdd without -munsafe-fp-atomics lowers to CAS loops
// (global: ~300cyc round trip per attempt, 64-way contention in the flush;
// possibly LDS too) -> the occupancy/ILP-invariant ~40us. Fix:
//   stage 1: LDS hist via unsafeAtomicAdd (native ds_add_f32), plain
//            coalesced stores of partials to ws (no global atomics).
//   stage 2: per-block 256 consecutive bins, loop over 64 partials ->
//            fully coalesced loads, 4-way ILP, plain stores to d_out.

constexpr int RAD_N = 5, AZI_N = 30, ELE_N = 15;
constexpr int BINS  = RAD_N * AZI_N * ELE_N;   // 2250
constexpr int BLOCK = 256;
constexpr int PPT   = 4;                       // points per thread (stage 1)
constexpr int PPB   = BLOCK * PPT;             // 1024
constexpr int RCHUNK = 256;                    // bins per reduce block
constexpr int RCHUNKS = (BINS + RCHUNK - 1) / RCHUNK;  // 9

__device__ __forceinline__ float fast_atan2_02pi(float y, float x) {
    const float PI_F     = 3.14159265358979f;
    const float TWO_PI_F = 6.28318530717959f;
    const float HALF_PI  = 1.57079632679490f;
    float ax = fabsf(x), ay = fabsf(y);
    float mx = fmaxf(ax, ay), mn = fminf(ax, ay);
    float t  = mn * __builtin_amdgcn_rcpf(mx);
    float t2 = t * t;
    float p = -0.01172120f;
    p = __builtin_fmaf(p, t2,  0.05265332f);
    p = __builtin_fmaf(p, t2, -0.11643287f);
    p = __builtin_fmaf(p, t2,  0.19354346f);
    p = __builtin_fmaf(p, t2, -0.33262347f);
    p = __builtin_fmaf(p, t2,  0.99997726f);
    float th = t * p;                          // [0, pi/4]
    th = (ay > ax) ? (HALF_PI - th) : th;      // [0, pi/2]
    th = (x < 0.0f) ? (PI_F - th) : th;        // [0, pi]
    th = (y < 0.0f) ? (TWO_PI_F - th) : th;    // [0, 2pi)
    return th;
}

__device__ __forceinline__ float fast_acos(float x) {
    const float PI_F = 3.14159265358979f;
    float a = fabsf(x);
    float p = -0.0012624911f;
    p = __builtin_fmaf(p, a,  0.0066700901f);
    p = __builtin_fmaf(p, a, -0.0170881256f);
    p = __builtin_fmaf(p, a,  0.0308918810f);
    p = __builtin_fmaf(p, a, -0.0501743046f);
    p = __builtin_fmaf(p, a,  0.0889789874f);
    p = __builtin_fmaf(p, a, -0.2145988016f);
    p = __builtin_fmaf(p, a,  1.5707963050f);
    float s = __builtin_amdgcn_sqrtf(1.0f - a);
    float r = s * p;
    return (x < 0.0f) ? (PI_F - r) : r;
}

__device__ __forceinline__ void process_point(float x, float y, float z, float* hist) {
    const float TWO_PI_F = (float)(6.283185307179586);
    const float PI_F     = (float)(3.141592653589793);
    const float tr       = (float)(2.0 / 5.0);
    const float sr       = (float)(2.0 / 5.0 / 2.0);
    const float tr_p_sr  = (float)(0.4 + 0.2);
    const float rhi_lo   = (float)(2.0 - 0.2);
    const float DES_R_F  = 2.0f;
    const float ta       = (float)(6.283185307179586 / 30.0);
    const float te       = (float)(3.141592653589793 / 15.0);
    const float se       = (float)(3.141592653589793 / 30.0);
    const float te_p_se  = (float)(3.141592653589793 / 15.0 + 3.141592653589793 / 30.0);
    const float te075    = (float)(0.75 * (3.141592653589793 / 15.0));
    const float pi_m_se  = (float)(3.141592653589793 - 3.141592653589793 / 30.0);
    const float inv_tr   = (float)(5.0 / 2.0);
    const float inv_ta   = (float)(30.0 / 6.283185307179586);
    const float inv_te   = (float)(15.0 / 3.141592653589793);

    float r = __builtin_amdgcn_sqrtf(x * x + y * y + z * z);
    if (r > DES_R_F) return;   // all 8 weights exactly 0 in reference

    float azi = fast_atan2_02pi(y, x);
    float cz = z * __builtin_amdgcn_rcpf(fmaxf(r, 1e-12f));
    cz = fminf(fmaxf(cz, -1.0f), 1.0f);
    float ele = fast_acos(cz);

    // ---- radial: two nearest bins ----
    int ra = (int)(r * inv_tr);
    if (ra > RAD_N - 1) ra = RAD_N - 1;
    float cra = ((float)ra + 0.5f) * tr;
    int rb = (r > cra) ? ra + 1 : ra - 1;
    rb = (rb < 0) ? 1 : ((rb > RAD_N - 1) ? RAD_N - 2 : rb);
    float dra = fabsf(r - cra);
    float drb = fabsf(r - ((float)rb + 0.5f) * tr);
    {
        bool lowR  = r < sr;
        bool highR = (r > rhi_lo);
        if (lowR) {
            dra = (dra <= sr) ? 0.0f : ((dra > tr && dra <= tr_p_sr) ? tr : dra);
            drb = (drb <= sr) ? 0.0f : ((drb > tr && drb <= tr_p_sr) ? tr : drb);
        }
        if (highR) {
            if (dra > tr && dra <= tr_p_sr) dra = tr;
            if (drb > tr && drb <= tr_p_sr) drb = tr;
        }
    }
    float wra = 1.0f - dra * inv_tr;
    float wrb = 1.0f - drb * inv_tr;

    // ---- azimuth (circular) ----
    int aa = (int)(azi * inv_ta);
    if (aa > AZI_N - 1) aa = AZI_N - 1;
    float caa = ((float)aa + 0.5f) * ta;
    int ab = (azi > caa) ? aa + 1 : aa - 1;
    ab = (ab < 0) ? AZI_N - 1 : ((ab > AZI_N - 1) ? 0 : ab);
    float daa = fabsf(azi - caa);
    daa = fminf(daa, TWO_PI_F - daa);
    float dab = fabsf(azi - ((float)ab + 0.5f) * ta);
    dab = fminf(dab, TWO_PI_F - dab);
    float waa = 1.0f - daa * inv_ta;
    float wab = 1.0f - dab * inv_ta;

    // ---- elevation ----
    int ea = (int)(ele * inv_te);
    if (ea > ELE_N - 1) ea = ELE_N - 1;
    float cea = ((float)ea + 0.5f) * te;
    int eb = (ele > cea) ? ea + 1 : ea - 1;
    eb = (eb < 0) ? 1 : ((eb > ELE_N - 1) ? ELE_N - 2 : eb);
    float dea = fabsf(ele - cea);
    float deb = fabsf(ele - ((float)eb + 0.5f) * te);
    {
        bool lowE  = ele < se;
        bool highE = (ele > pi_m_se) && (ele <= PI_F);
        if (lowE) {
            dea = (dea <= se) ? 0.0f : ((dea > te && dea <= te_p_se) ? te : dea);
            deb = (deb <= se) ? 0.0f : ((deb > te && deb <= te_p_se) ? te : deb);
        }
        if (highE) {
            dea = (dea <= te075) ? 0.0f : ((dea > te && dea <= te_p_se) ? te : dea);
            deb = (deb <= te075) ? 0.0f : ((deb > te && deb <= te_p_se) ? te : deb);
        }
    }
    float wea = 1.0f - dea * inv_te;
    float web = 1.0f - deb * inv_te;

    int rbase_a = ra * (AZI_N * ELE_N), rbase_b = rb * (AZI_N * ELE_N);
    int abase_a = aa * ELE_N,           abase_b = ab * ELE_N;
    float w_aa = wra * waa, w_ab = wra * wab;
    float w_ba = wrb * waa, w_bb = wrb * wab;

    // unsafeAtomicAdd -> native ds_add_f32 (no CAS loop) on LDS
    unsafeAtomicAdd(&hist[rbase_a + abase_a + ea], w_aa * wea);
    unsafeAtomicAdd(&hist[rbase_a + abase_a + eb], w_aa * web);
    unsafeAtomicAdd(&hist[rbase_a + abase_b + ea], w_ab * wea);
    unsafeAtomicAdd(&hist[rbase_a + abase_b + eb], w_ab * web);
    unsafeAtomicAdd(&hist[rbase_b + abase_a + ea], w_ba * wea);
    unsafeAtomicAdd(&hist[rbase_b + abase_a + eb], w_ba * web);
    unsafeAtomicAdd(&hist[rbase_b + abase_b + ea], w_bb * wea);
    unsafeAtomicAdd(&hist[rbase_b + abase_b + eb], w_bb * web);
}

// Stage 1: per-block private LDS hist -> plain coalesced stores to ws
__global__ __launch_bounds__(BLOCK) void voxel_partial(
    const float* __restrict__ pts, float* __restrict__ ws,
    int N, int blocksPerBatch)
{
    __shared__ float hist[BINS];
    for (int j = threadIdx.x; j < BINS; j += BLOCK) hist[j] = 0.0f;
    __syncthreads();

    const int batch = blockIdx.x / blocksPerBatch;
    const int bib   = blockIdx.x % blocksPerBatch;
    const size_t batch_off = (size_t)batch * N;
    const int i0 = bib * PPB + (int)threadIdx.x * PPT;

    if (i0 + PPT <= N) {
        const float4* src = (const float4*)(pts + (batch_off + i0) * 3);
        float4 q0 = src[0];
        float4 q1 = src[1];
        float4 q2 = src[2];
        float X[PPT] = { q0.x, q0.w, q1.z, q2.y };
        float Y[PPT] = { q0.y, q1.x, q1.w, q2.z };
        float Z[PPT] = { q0.z, q1.y, q2.x, q2.w };
#pragma unroll
        for (int k = 0; k < PPT; ++k)
            process_point(X[k], Y[k], Z[k], hist);
    } else {
        for (int k = 0; k < PPT; ++k) {
            int i = i0 + k;
            if (i < N) {
                size_t p = (batch_off + i) * 3;
                process_point(pts[p], pts[p + 1], pts[p + 2], hist);
            }
        }
    }

    __syncthreads();
    float* wb = ws + (size_t)blockIdx.x * BINS;
    for (int j = threadIdx.x; j < BINS; j += BLOCK) wb[j] = hist[j];
}

// Stage 2: block = (batch, chunk of 256 consecutive bins); loop over
// partials -> every load coalesced; 4 independent accumulators; plain store.
__global__ __launch_bounds__(RCHUNK) void voxel_reduce(
    const float* __restrict__ ws, float* __restrict__ out,
    int blocksPerBatch)
{
    int batch = blockIdx.x / RCHUNKS;
    int chunk = blockIdx.x % RCHUNKS;
    int bin = chunk * RCHUNK + (int)threadIdx.x;
    if (bin >= BINS) return;

    const float* src = ws + (size_t)batch * blocksPerBatch * BINS + bin;
    float s0 = 0.0f, s1 = 0.0f, s2 = 0.0f, s3 = 0.0f;
    int k = 0;
    for (; k + 3 < blocksPerBatch; k += 4) {
        float a0 = src[(size_t)(k + 0) * BINS];
        float a1 = src[(size_t)(k + 1) * BINS];
        float a2 = src[(size_t)(k + 2) * BINS];
        float a3 = src[(size_t)(k + 3) * BINS];
        s0 += a0; s1 += a1; s2 += a2; s3 += a3;
    }
    for (; k < blocksPerBatch; ++k) s0 += src[(size_t)k * BINS];
    out[(size_t)batch * BINS + bin] = (s0 + s1) + (s2 + s3);
}

extern "C" void kernel_launch(void* const* d_in, const int* in_sizes, int n_in,
                              void* d_out, int out_size, void* d_ws, size_t ws_size,
                              hipStream_t stream) {
    const float* pts = (const float*)d_in[0];
    float* out = (float*)d_out;

    const int B = 16;
    int total = in_sizes[0] / 3;                 // B*N
    int N = total / B;                           // 65536
    int blocksPerBatch = (N + PPB - 1) / PPB;    // 64
    int grid = B * blocksPerBatch;               // 1024

    float* ws = (float*)d_ws;                    // needs 9.2 MB; ws is ~256 MB
    voxel_partial<<<dim3(grid), dim3(BLOCK), 0, stream>>>(pts, ws, N, blocksPerBatch);
    voxel_reduce<<<dim3(B * RCHUNKS), dim3(RCHUNK), 0, stream>>>(ws, out, blocksPerBatch);
}

// Round 7
// 71.509 us; speedup vs baseline: 1.3718x; 1.3718x over previous
//
#include <hip/hip_runtime.h>
#include <math.h>

// Spherical voxelization: points [B,N,3] f32 -> hist [B,1,5,30,15] f32
// B=16, N=65536, bins = 5*30*15 = 2250.
// R7 theory: fp32 atomicAdd (incl. LDS) compiles to a CAS retry loop without
// -munsafe-fp-atomics -> the invariant ~43us. Integer atomics are ALWAYS a
// single native instruction (ds_add_u32 / global_atomic_add_u32), so we
// accumulate in fixed point (scale 2^21) and convert at the end.

constexpr int RAD_N = 5, AZI_N = 30, ELE_N = 15;
constexpr int BINS  = RAD_N * AZI_N * ELE_N;   // 2250
constexpr int BLOCK = 256;
constexpr int PPT   = 4;                       // points per thread
constexpr int PPB   = BLOCK * PPT;             // 1024
constexpr float FX_SCALE   = 2097152.0f;       // 2^21
constexpr float FX_INV     = 1.0f / 2097152.0f;

__device__ __forceinline__ float fast_atan2_02pi(float y, float x) {
    const float PI_F     = 3.14159265358979f;
    const float TWO_PI_F = 6.28318530717959f;
    const float HALF_PI  = 1.57079632679490f;
    float ax = fabsf(x), ay = fabsf(y);
    float mx = fmaxf(ax, ay), mn = fminf(ax, ay);
    float t  = mn * __builtin_amdgcn_rcpf(mx);
    float t2 = t * t;
    float p = -0.01172120f;
    p = __builtin_fmaf(p, t2,  0.05265332f);
    p = __builtin_fmaf(p, t2, -0.11643287f);
    p = __builtin_fmaf(p, t2,  0.19354346f);
    p = __builtin_fmaf(p, t2, -0.33262347f);
    p = __builtin_fmaf(p, t2,  0.99997726f);
    float th = t * p;                          // [0, pi/4]
    th = (ay > ax) ? (HALF_PI - th) : th;      // [0, pi/2]
    th = (x < 0.0f) ? (PI_F - th) : th;        // [0, pi]
    th = (y < 0.0f) ? (TWO_PI_F - th) : th;    // [0, 2pi)
    return th;
}

__device__ __forceinline__ float fast_acos(float x) {
    const float PI_F = 3.14159265358979f;
    float a = fabsf(x);
    float p = -0.0012624911f;
    p = __builtin_fmaf(p, a,  0.0066700901f);
    p = __builtin_fmaf(p, a, -0.0170881256f);
    p = __builtin_fmaf(p, a,  0.0308918810f);
    p = __builtin_fmaf(p, a, -0.0501743046f);
    p = __builtin_fmaf(p, a,  0.0889789874f);
    p = __builtin_fmaf(p, a, -0.2145988016f);
    p = __builtin_fmaf(p, a,  1.5707963050f);
    float s = __builtin_amdgcn_sqrtf(1.0f - a);
    float r = s * p;
    return (x < 0.0f) ? (PI_F - r) : r;
}

__device__ __forceinline__ unsigned to_fx(float w) {
    // w in [-eps, 1]; round to nearest, clamp negatives to 0 via the cast
    float v = __builtin_fmaf(w, FX_SCALE, 0.5f);
    return (unsigned)fmaxf(v, 0.0f);
}

__device__ __forceinline__ void process_point(float x, float y, float z,
                                              unsigned* hist) {
    const float TWO_PI_F = (float)(6.283185307179586);
    const float PI_F     = (float)(3.141592653589793);
    const float tr       = (float)(2.0 / 5.0);
    const float sr       = (float)(2.0 / 5.0 / 2.0);
    const float tr_p_sr  = (float)(0.4 + 0.2);
    const float rhi_lo   = (float)(2.0 - 0.2);
    const float DES_R_F  = 2.0f;
    const float ta       = (float)(6.283185307179586 / 30.0);
    const float te       = (float)(3.141592653589793 / 15.0);
    const float se       = (float)(3.141592653589793 / 30.0);
    const float te_p_se  = (float)(3.141592653589793 / 15.0 + 3.141592653589793 / 30.0);
    const float te075    = (float)(0.75 * (3.141592653589793 / 15.0));
    const float pi_m_se  = (float)(3.141592653589793 - 3.141592653589793 / 30.0);
    const float inv_tr   = (float)(5.0 / 2.0);
    const float inv_ta   = (float)(30.0 / 6.283185307179586);
    const float inv_te   = (float)(15.0 / 3.141592653589793);

    float r = __builtin_amdgcn_sqrtf(x * x + y * y + z * z);
    if (r > DES_R_F) return;   // all 8 weights exactly 0 in reference

    float azi = fast_atan2_02pi(y, x);
    float cz = z * __builtin_amdgcn_rcpf(fmaxf(r, 1e-12f));
    cz = fminf(fmaxf(cz, -1.0f), 1.0f);
    float ele = fast_acos(cz);

    // ---- radial: two nearest bins ----
    int ra = (int)(r * inv_tr);
    if (ra > RAD_N - 1) ra = RAD_N - 1;
    float cra = ((float)ra + 0.5f) * tr;
    int rb = (r > cra) ? ra + 1 : ra - 1;
    rb = (rb < 0) ? 1 : ((rb > RAD_N - 1) ? RAD_N - 2 : rb);
    float dra = fabsf(r - cra);
    float drb = fabsf(r - ((float)rb + 0.5f) * tr);
    {
        bool lowR  = r < sr;
        bool highR = (r > rhi_lo);
        if (lowR) {
            dra = (dra <= sr) ? 0.0f : ((dra > tr && dra <= tr_p_sr) ? tr : dra);
            drb = (drb <= sr) ? 0.0f : ((drb > tr && drb <= tr_p_sr) ? tr : drb);
        }
        if (highR) {
            if (dra > tr && dra <= tr_p_sr) dra = tr;
            if (drb > tr && drb <= tr_p_sr) drb = tr;
        }
    }
    float wra = 1.0f - dra * inv_tr;
    float wrb = 1.0f - drb * inv_tr;

    // ---- azimuth (circular) ----
    int aa = (int)(azi * inv_ta);
    if (aa > AZI_N - 1) aa = AZI_N - 1;
    float caa = ((float)aa + 0.5f) * ta;
    int ab = (azi > caa) ? aa + 1 : aa - 1;
    ab = (ab < 0) ? AZI_N - 1 : ((ab > AZI_N - 1) ? 0 : ab);
    float daa = fabsf(azi - caa);
    daa = fminf(daa, TWO_PI_F - daa);
    float dab = fabsf(azi - ((float)ab + 0.5f) * ta);
    dab = fminf(dab, TWO_PI_F - dab);
    float waa = 1.0f - daa * inv_ta;
    float wab = 1.0f - dab * inv_ta;

    // ---- elevation ----
    int ea = (int)(ele * inv_te);
    if (ea > ELE_N - 1) ea = ELE_N - 1;
    float cea = ((float)ea + 0.5f) * te;
    int eb = (ele > cea) ? ea + 1 : ea - 1;
    eb = (eb < 0) ? 1 : ((eb > ELE_N - 1) ? ELE_N - 2 : eb);
    float dea = fabsf(ele - cea);
    float deb = fabsf(ele - ((float)eb + 0.5f) * te);
    {
        bool lowE  = ele < se;
        bool highE = (ele > pi_m_se) && (ele <= PI_F);
        if (lowE) {
            dea = (dea <= se) ? 0.0f : ((dea > te && dea <= te_p_se) ? te : dea);
            deb = (deb <= se) ? 0.0f : ((deb > te && deb <= te_p_se) ? te : deb);
        }
        if (highE) {
            dea = (dea <= te075) ? 0.0f : ((dea > te && dea <= te_p_se) ? te : dea);
            deb = (deb <= te075) ? 0.0f : ((deb > te && deb <= te_p_se) ? te : deb);
        }
    }
    float wea = 1.0f - dea * inv_te;
    float web = 1.0f - deb * inv_te;

    int rbase_a = ra * (AZI_N * ELE_N), rbase_b = rb * (AZI_N * ELE_N);
    int abase_a = aa * ELE_N,           abase_b = ab * ELE_N;
    float w_aa = wra * waa, w_ab = wra * wab;
    float w_ba = wrb * waa, w_bb = wrb * wab;

    // Native integer atomics: ds_add_u32 (never a CAS loop)
    atomicAdd(&hist[rbase_a + abase_a + ea], to_fx(w_aa * wea));
    atomicAdd(&hist[rbase_a + abase_a + eb], to_fx(w_aa * web));
    atomicAdd(&hist[rbase_a + abase_b + ea], to_fx(w_ab * wea));
    atomicAdd(&hist[rbase_a + abase_b + eb], to_fx(w_ab * web));
    atomicAdd(&hist[rbase_b + abase_a + ea], to_fx(w_ba * wea));
    atomicAdd(&hist[rbase_b + abase_a + eb], to_fx(w_ba * web));
    atomicAdd(&hist[rbase_b + abase_b + ea], to_fx(w_bb * wea));
    atomicAdd(&hist[rbase_b + abase_b + eb], to_fx(w_bb * web));
}

// Stage 1: LDS u32 hist; flush via native global_atomic_add_u32 into ws
__global__ __launch_bounds__(BLOCK) void voxel_u32(
    const float* __restrict__ pts, unsigned* __restrict__ ws_u,
    int N, int blocksPerBatch)
{
    __shared__ unsigned hist[BINS];
    for (int j = threadIdx.x; j < BINS; j += BLOCK) hist[j] = 0u;
    __syncthreads();

    const int batch = blockIdx.x / blocksPerBatch;
    const int bib   = blockIdx.x % blocksPerBatch;
    const size_t batch_off = (size_t)batch * N;
    const int i0 = bib * PPB + (int)threadIdx.x * PPT;

    if (i0 + PPT <= N) {
        const float4* src = (const float4*)(pts + (batch_off + i0) * 3);
        float4 q0 = src[0];
        float4 q1 = src[1];
        float4 q2 = src[2];
        float X[PPT] = { q0.x, q0.w, q1.z, q2.y };
        float Y[PPT] = { q0.y, q1.x, q1.w, q2.z };
        float Z[PPT] = { q0.z, q1.y, q2.x, q2.w };
#pragma unroll
        for (int k = 0; k < PPT; ++k)
            process_point(X[k], Y[k], Z[k], hist);
    } else {
        for (int k = 0; k < PPT; ++k) {
            int i = i0 + k;
            if (i < N) {
                size_t p = (batch_off + i) * 3;
                process_point(pts[p], pts[p + 1], pts[p + 2], hist);
            }
        }
    }

    __syncthreads();
    unsigned* ob = ws_u + (size_t)batch * BINS;
    for (int j = threadIdx.x; j < BINS; j += BLOCK) {
        unsigned v = hist[j];
        if (v) atomicAdd(&ob[j], v);   // native global_atomic_add u32
    }
}

// Stage 2: convert fixed-point accumulators to float output
__global__ __launch_bounds__(BLOCK) void fx_convert(
    const unsigned* __restrict__ ws_u, float* __restrict__ out, int total)
{
    int i = blockIdx.x * BLOCK + (int)threadIdx.x;
    if (i < total) out[i] = (float)ws_u[i] * FX_INV;
}

extern "C" void kernel_launch(void* const* d_in, const int* in_sizes, int n_in,
                              void* d_out, int out_size, void* d_ws, size_t ws_size,
                              hipStream_t stream) {
    const float* pts = (const float*)d_in[0];
    float* out = (float*)d_out;

    const int B = 16;
    int total = in_sizes[0] / 3;                 // B*N
    int N = total / B;                           // 65536
    int blocksPerBatch = (N + PPB - 1) / PPB;    // 64
    int grid = B * blocksPerBatch;               // 1024

    unsigned* ws_u = (unsigned*)d_ws;            // B*BINS u32 = 144 KB
    int rtotal = B * BINS;                       // 36000
    hipMemsetAsync(d_ws, 0, (size_t)rtotal * sizeof(unsigned), stream);
    voxel_u32<<<dim3(grid), dim3(BLOCK), 0, stream>>>(pts, ws_u, N, blocksPerBatch);
    fx_convert<<<dim3((rtotal + BLOCK - 1) / BLOCK), dim3(BLOCK), 0, stream>>>(
        ws_u, out, rtotal);
}